// Round 9
// baseline (2269.892 us; speedup 1.0000x reference)
//
#include <hip/hip_runtime.h>

#define B_ 8
#define C_ 3
#define H_ 256
#define W_ 256
#define HID_ 32
#define HW_ (H_*W_)            // 65536
#define N_ (B_*H_*W_)          // 524288
#define K01_ 0xBDCCCCCDu       // fkey(0.1f)
#define TILE_ 16
#define SEGE_ 131072           // per-image edge-list capacity (>= 130560)
#define SEGR_ 65536            // per-image region-list capacity

// XCD-chunked swizzle for 2048-block grids: consecutive hardware block ids
// round-robin across 8 XCDs; remap so XCD x owns image x (bid&7 == image).
__device__ __forceinline__ int swz2048(int bid){ return ((bid & 7) << 8) | (bid >> 3); }

__device__ __forceinline__ unsigned fkey(float f){
  unsigned u = __float_as_uint(f);
  return (u & 0x80000000u) ? ~u : (u | 0x80000000u);
}

// mk entry: [63:56]=tag | [55:24]=fkey(sim) | [23:0]=neighbor id (N<2^24).
// newer tag always wins; same tag -> (key,id) lex max == reference tie-break.
__device__ __forceinline__ unsigned long long pack_mk(unsigned tag, unsigned key, int id){
  return ((unsigned long long)tag << 56) | ((unsigned long long)key << 24) | (unsigned)id;
}

__device__ __forceinline__ int parent_dec(unsigned long long m, unsigned tag, int x){
  if ((unsigned)(m >> 56) != tag) return x;
  return ((unsigned)(m >> 24) > K01_) ? (int)(m & 0xFFFFFFu) : x;
}

// wave-aggregated list append; ALL 64 lanes must call (uniform control flow)
__device__ __forceinline__ int wave_append(int* counter, bool pred){
  unsigned long long m = __ballot(pred);
  if (m == 0ULL) return -1;
  int lane = threadIdx.x & 63;
  int leader = __ffsll((long long)m) - 1;
  int base = 0;
  if (lane == leader) base = atomicAdd(counter, __popcll(m));
  base = __shfl(base, leader);
  return base + __popcll(m & ((1ULL << lane) - 1ULL));
}

__device__ __forceinline__ void fold_into(int i, int x, float* __restrict__ fsum,
    float* __restrict__ psum, float* __restrict__ cnt){
  atomicAdd(cnt+x, cnt[i]);
  const float* s = fsum + (size_t)i*HID_;
  float* ds = fsum + (size_t)x*HID_;
  #pragma unroll
  for (int d=0; d<HID_; ++d) atomicAdd(ds+d, s[d]);
  const float* ps = psum + (size_t)i*C_;
  float* dp = psum + (size_t)x*C_;
  #pragma unroll
  for (int cc=0; cc<C_; ++cc) atomicAdd(dp+cc, ps[cc]);
}

__device__ __forceinline__ unsigned edge_key(int a, int b,
    const float* __restrict__ fsum, const float* __restrict__ cnt){
  float rca = 1.0f / cnt[a], rcb = 1.0f / cnt[b];
  const float4* fa = (const float4*)(fsum + (size_t)a*HID_);
  const float4* fb = (const float4*)(fsum + (size_t)b*HID_);
  float d2 = 0.f;
  #pragma unroll
  for (int k=0; k<HID_/4; ++k){
    float4 va = fa[k], vb = fb[k];
    float t0 = va.x*rca - vb.x*rcb; float t1 = va.y*rca - vb.y*rcb;
    float t2 = va.z*rca - vb.z*rcb; float t3 = va.w*rca - vb.w*rcb;
    d2 += t0*t0 + t1*t1 + t2*t2 + t3*t3;
  }
  return fkey(expf(-d2));
}

// 16x16-tile conv + init (par=iota) + it0 in-tile sims via wave shuffles
// (lane layout r = wv*4 + (lane>>4), c = lane&15). Cross-tile edges: k_bedge.
__global__ __launch_bounds__(256) void k_conv_init(const float* __restrict__ img,
    const float* __restrict__ cw, const float* __restrict__ cb,
    float* __restrict__ fsum, int* __restrict__ par,
    float* __restrict__ cnt, float* __restrict__ psum,
    unsigned long long* __restrict__ mk){
  __shared__ float w_s[HID_*C_*9];
  __shared__ float b_s[HID_];
  __shared__ float img_s[C_][TILE_+2][TILE_+3];   // 3 x 18 x 19
  __shared__ float rowbuf[3*TILE_][33];           // rows 4,8,12 cross-wave
  for (int t = threadIdx.x; t < HID_*C_*9; t += blockDim.x) w_s[t] = cw[t];
  if (threadIdx.x < HID_) b_s[threadIdx.x] = cb[threadIdx.x];

  int sb = swz2048(blockIdx.x);
  int b  = sb >> 8;
  int ti = sb & 255;
  int h0 = (ti >> 4) * TILE_;
  int w0 = (ti & 15) * TILE_;

  for (int t = threadIdx.x; t < C_*18*18; t += blockDim.x){
    int ci = t / 324; int rm = t - ci*324; int rr = rm / 18; int cc = rm - rr*18;
    int hh = h0 - 1 + rr, ww = w0 - 1 + cc;
    float v = 0.f;
    if (hh >= 0 && hh < H_ && ww >= 0 && ww < W_)
      v = img[(size_t)(b*C_+ci)*HW_ + hh*W_ + ww];
    img_s[ci][rr][cc] = v;
  }
  __syncthreads();

  int lane = threadIdx.x & 63, wv = threadIdx.x >> 6;
  int r = wv*4 + (lane >> 4);
  int c = lane & 15;
  int h = h0 + r, w = w0 + c;
  int i = (b << 16) | (h << 8) | w;

  float patch[C_*9];
  #pragma unroll
  for (int ci=0; ci<C_; ++ci)
    #pragma unroll
    for (int kh=0; kh<3; ++kh)
      #pragma unroll
      for (int kw=0; kw<3; ++kw)
        patch[ci*9+kh*3+kw] = img_s[ci][r+kh][c+kw];

  float acc[HID_];
  #pragma unroll 4
  for (int oc=0; oc<HID_; ++oc){
    float a = b_s[oc];
    const float* ws = w_s + oc*C_*9;
    #pragma unroll
    for (int t=0; t<C_*9; ++t) a += patch[t]*ws[t];
    acc[oc] = a;
  }

  {
    float4* o4 = (float4*)(fsum + (size_t)i*HID_);
    #pragma unroll
    for (int k=0; k<HID_/4; ++k)
      o4[k] = make_float4(acc[4*k], acc[4*k+1], acc[4*k+2], acc[4*k+3]);
  }
  par[i] = i;
  cnt[i] = 1.0f;
  #pragma unroll
  for (int cc=0; cc<C_; ++cc) psum[(size_t)i*C_+cc] = img_s[cc][r+1][c+1];

  if (wv >= 1 && lane < 16){
    float* dst = rowbuf[(wv-1)*TILE_ + c];
    #pragma unroll
    for (int d=0; d<HID_; ++d) dst[d] = acc[d];
  }

  float d2R = 0.f;
  #pragma unroll
  for (int k=0; k<HID_/4; ++k){
    float t0 = acc[4*k]   - __shfl_down(acc[4*k],  1);
    float t1 = acc[4*k+1] - __shfl_down(acc[4*k+1],1);
    float t2 = acc[4*k+2] - __shfl_down(acc[4*k+2],1);
    float t3 = acc[4*k+3] - __shfl_down(acc[4*k+3],1);
    d2R += t0*t0 + t1*t1 + t2*t2 + t3*t3;
  }
  float d2D = 0.f;
  #pragma unroll
  for (int k=0; k<HID_/4; ++k){
    float t0 = acc[4*k]   - __shfl_down(acc[4*k],  16);
    float t1 = acc[4*k+1] - __shfl_down(acc[4*k+1],16);
    float t2 = acc[4*k+2] - __shfl_down(acc[4*k+2],16);
    float t3 = acc[4*k+3] - __shfl_down(acc[4*k+3],16);
    d2D += t0*t0 + t1*t1 + t2*t2 + t3*t3;
  }
  __syncthreads();
  if (lane >= 48 && wv < 3){          // row 4wv+3: neighbor row in wave wv+1
    const float* nb = rowbuf[wv*TILE_ + c];
    d2D = 0.f;
    #pragma unroll
    for (int k=0; k<HID_/4; ++k){
      float t0 = acc[4*k]   - nb[4*k];
      float t1 = acc[4*k+1] - nb[4*k+1];
      float t2 = acc[4*k+2] - nb[4*k+2];
      float t3 = acc[4*k+3] - nb[4*k+3];
      d2D += t0*t0 + t1*t1 + t2*t2 + t3*t3;
    }
  }

  if (c < TILE_-1){
    unsigned key = fkey(expf(-d2R));
    atomicMax(mk+i,   pack_mk(1u, key, i+1));
    atomicMax(mk+i+1, pack_mk(1u, key, i));
  }
  if (r < TILE_-1){
    unsigned key = fkey(expf(-d2D));
    atomicMax(mk+i,     pack_mk(1u, key, i+W_));
    atomicMax(mk+i+W_,  pack_mk(1u, key, i));
  }
}

// cross-tile it0 edges
__global__ void k_bedge(const float* __restrict__ fsum,
                        unsigned long long* __restrict__ mk){
  int t = blockIdx.x*blockDim.x + threadIdx.x;
  if (t >= B_*2*15*256) return;
  int y  = t & 255;
  int k  = (t >> 8) % 15;
  int ty = (t >> 8) / 15;
  int b  = ty >> 1, tp = ty & 1;
  int i, j;
  if (tp == 0){ i = (b<<16) | (y<<8) | (16*k+15); j = i+1;  }
  else        { i = (b<<16) | ((16*k+15)<<8) | y; j = i+W_; }
  const float4* fa = (const float4*)(fsum + (size_t)i*HID_);
  const float4* fb = (const float4*)(fsum + (size_t)j*HID_);
  float d2 = 0.f;
  #pragma unroll
  for (int q=0; q<HID_/4; ++q){
    float4 va = fa[q], vb = fb[q];
    float t0 = va.x-vb.x, t1 = va.y-vb.y, t2 = va.z-vb.z, t3 = va.w-vb.w;
    d2 += t0*t0 + t1*t1 + t2*t2 + t3*t3;
  }
  unsigned key = fkey(expf(-d2));
  atomicMax(mk+i, pack_mk(1u, key, j));
  atomicMax(mk+j, pack_mk(1u, key, i));
}

// it0 update: every pixel is a live region. Chase tag1, fold dying roots,
// set par, append survivors to the per-image region list.
__global__ void k_upd0(const unsigned long long* __restrict__ mk,
    int* __restrict__ par, float* __restrict__ fsum, float* __restrict__ psum,
    float* __restrict__ cnt, int* __restrict__ rOut, int* __restrict__ cR){
  int i = swz2048(blockIdx.x)*256 + threadIdx.x;
  int seg = i >> 16;
  int x = i;
  for (int it = 0; it < (1<<20); ++it){
    int p = parent_dec(mk[x], 1u, x);
    if (p == x) break;
    int pp = parent_dec(mk[p], 1u, p);
    if (pp == x && x < p) break;     // broken 2-cycle: x is the root
    x = p;
  }
  bool died = (x != i);
  if (died){ fold_into(i, x, fsum, psum, cnt); par[i] = x; }
  int pos = wave_append(&cR[seg], !died);
  if (!died) rOut[(size_t)seg*SEGR_ + pos] = i;
}

// it1 sim pass over pixel adjacency: contract through par (1-level = exact
// root after upd0), emit region-edge list for later iters, sims tag 2.
__global__ void k_esim_pix(const int* __restrict__ par,
    const float* __restrict__ fsum, const float* __restrict__ cnt,
    unsigned long long* __restrict__ eOut, int* __restrict__ cE,
    unsigned long long* __restrict__ mk){
  int i = swz2048(blockIdx.x)*256 + threadIdx.x;
  int seg = i >> 16;
  int rem = i & (HW_-1); int h = rem >> 8; int w = rem & (W_-1);
  int a  = par[i];
  int bR = (w < W_-1) ? par[i+1]  : a;
  int bD = (h < H_-1) ? par[i+W_] : a;
  bool eR = (bR != a), eD = (bD != a);
  unsigned long long* eo = eOut + (size_t)seg*SEGE_;
  unsigned keyR = 0, keyD = 0;
  if (eR) keyR = edge_key(a, bR, fsum, cnt);
  if (eD) keyD = edge_key(a, bD, fsum, cnt);
  int posR = wave_append(&cE[seg], eR);
  if (eR){
    eo[posR] = ((unsigned long long)a << 32) | (unsigned)bR;
    atomicMax(mk+a,  pack_mk(2u, keyR, bR));
    atomicMax(mk+bR, pack_mk(2u, keyR, a));
  }
  int posD = wave_append(&cE[seg], eD);
  if (eD){
    eo[posD] = ((unsigned long long)a << 32) | (unsigned)bD;
    atomicMax(mk+a,  pack_mk(2u, keyD, bD));
    atomicMax(mk+bD, pack_mk(2u, keyD, a));
  }
}

// iter k>=2 sim pass: contract previous edge list through par, compact, sims.
__global__ void k_esim_edge(const unsigned long long* __restrict__ eIn,
    const int* __restrict__ cIn, unsigned long long* __restrict__ eOut,
    int* __restrict__ cOut, const int* __restrict__ par,
    const float* __restrict__ fsum, const float* __restrict__ cnt,
    unsigned long long* __restrict__ mk, unsigned tag){
  int seg = blockIdx.x & 7;
  int tl  = (blockIdx.x >> 3)*256 + threadIdx.x;   // 0..65535 in segment
  int n = cIn[seg];
  const unsigned long long* ein = eIn + (size_t)seg*SEGE_;
  unsigned long long* eo = eOut + (size_t)seg*SEGE_;
  #pragma unroll
  for (int s = 0; s < 2; ++s){
    int t = s*65536 + tl;
    bool act = (t < n);
    int a = 0, b = 0;
    if (act){
      unsigned long long e = ein[t];
      a = par[(int)(e >> 32)];
      b = par[(int)(e & 0xffffffffu)];
      act = (a != b);
    }
    unsigned key = 0;
    if (act) key = edge_key(a, b, fsum, cnt);
    int pos = wave_append(&cOut[seg], act);
    if (act){
      eo[pos] = ((unsigned long long)a << 32) | (unsigned)b;
      atomicMax(mk+a, pack_mk(tag, key, b));
      atomicMax(mk+b, pack_mk(tag, key, a));
    }
  }
}

// iter k>=1 update over live-region list: chase, fold, set par, compact survivors.
__global__ void k_eupd(const int* __restrict__ rIn, const int* __restrict__ cIn,
    int* __restrict__ rOut, int* __restrict__ cOut,
    const unsigned long long* __restrict__ mk, unsigned tag,
    int* __restrict__ par, float* __restrict__ fsum, float* __restrict__ psum,
    float* __restrict__ cnt){
  int seg = blockIdx.x & 7;
  int t   = (blockIdx.x >> 3)*256 + threadIdx.x;
  int n = cIn[seg];
  bool act = (t < n);
  int r = 0;
  if (act) r = rIn[(size_t)seg*SEGR_ + t];
  int x = r;
  if (act){
    for (int it = 0; it < (1<<20); ++it){
      int p = parent_dec(mk[x], tag, x);
      if (p == x) break;
      int pp = parent_dec(mk[p], tag, p);
      if (pp == x && x < p) break;   // broken 2-cycle: x is the root
      x = p;
    }
  }
  bool died = act && (x != r);
  if (died){ fold_into(r, x, fsum, psum, cnt); par[r] = x; }
  bool surv = act && !died;
  int pos = wave_append(&cOut[seg], surv);
  if (surv) rOut[(size_t)seg*SEGR_ + pos] = r;
}

// finalize: chase par (<=8 hops), region feature at root, mean injection.
__global__ __launch_bounds__(256) void k_final(const int* __restrict__ par,
      const float* __restrict__ img, const float* __restrict__ cnt,
      const float* __restrict__ fsum, const float* __restrict__ psum,
      const float* __restrict__ lw, const float* __restrict__ lb,
      float* __restrict__ out, float* __restrict__ outlab){
  __shared__ float lw_s[C_*HID_];
  __shared__ float lb_s[C_];
  for (int t = threadIdx.x; t < C_*HID_; t += blockDim.x) lw_s[t] = lw[t];
  if (threadIdx.x < C_) lb_s[threadIdx.x] = lb[threadIdx.x];
  __syncthreads();
  int i = swz2048(blockIdx.x)*256 + threadIdx.x;
  int l = i;
  for (int q = 0; q < 64; ++q){
    int p = par[l];
    if (p == l) break;
    l = p;
  }
  float rc = 1.0f / cnt[l];
  const float* s = fsum + (size_t)l*HID_;
  float rf[C_];
  #pragma unroll
  for (int cc=0; cc<C_; ++cc){
    float a = 0.f;
    const float* wv = lw_s + cc*HID_;
    #pragma unroll
    for (int d=0; d<HID_; ++d) a += (s[d]*rc)*wv[d];
    rf[cc] = (a + lb_s[cc]) - psum[(size_t)l*C_+cc]*rc;
  }
  int b = i >> 16; int rem = i & (HW_-1);
  const float* ip = img + (size_t)b*C_*HW_ + rem;
  #pragma unroll
  for (int cc=0; cc<C_; ++cc)
    out[(size_t)i*C_+cc] = ip[(size_t)cc*HW_] + rf[cc];
  outlab[i] = (float)l;
}

extern "C" void kernel_launch(void* const* d_in, const int* in_sizes, int n_in,
                              void* d_out, int out_size, void* d_ws, size_t ws_size,
                              hipStream_t stream) {
  const float* img = (const float*)d_in[0];
  const float* cw  = (const float*)d_in[1];
  const float* cb  = (const float*)d_in[2];
  const float* lw  = (const float*)d_in[3];
  const float* lb  = (const float*)d_in[4];

  char* ws = (char*)d_ws;
  size_t off = 0;
  auto alloc = [&](size_t bytes) -> void* {
    void* p = ws + off; off += (bytes + 255) & ~(size_t)255; return p;
  };
  float*              fsum  = (float*)              alloc((size_t)N_*HID_*4);
  float*              psum  = (float*)              alloc((size_t)N_*C_*4);
  float*              cnt   = (float*)              alloc((size_t)N_*4);
  unsigned long long* mk    = (unsigned long long*) alloc((size_t)N_*8);
  int*                par   = (int*)                alloc((size_t)N_*4);
  unsigned long long* eBuf0 = (unsigned long long*) alloc((size_t)8*SEGE_*8);
  unsigned long long* eBuf1 = (unsigned long long*) alloc((size_t)8*SEGE_*8);
  int*                rBuf0 = (int*)                alloc((size_t)8*SEGR_*4);
  int*                rBuf1 = (int*)                alloc((size_t)8*SEGR_*4);
  int*                ctr   = (int*)                alloc(1024);
  // counters: cR[it][seg] = ctr[it*8+seg] (it=0..7), cE[j][seg] = ctr[64+j*8+seg]

  dim3 blk(256);
  const int gN = 2048;

  hipMemsetAsync(mk,  0, (size_t)N_*8, stream);   // clear poison + stale tags
  hipMemsetAsync(ctr, 0, 1024, stream);
  k_conv_init<<<gN, blk, 0, stream>>>(img, cw, cb, fsum, par, cnt, psum, mk);
  k_bedge<<<240, blk, 0, stream>>>(fsum, mk);
  k_upd0<<<gN, blk, 0, stream>>>(mk, par, fsum, psum, cnt, rBuf0, ctr);
  // iter 1
  k_esim_pix<<<gN, blk, 0, stream>>>(par, fsum, cnt, eBuf0, ctr+64, mk);
  k_eupd<<<gN, blk, 0, stream>>>(rBuf0, ctr, rBuf1, ctr+8, mk, 2u,
                                 par, fsum, psum, cnt);
  // iters 2..7
  for (int k = 2; k < 8; ++k){
    unsigned long long* eIn  = (k & 1) ? eBuf1 : eBuf0;
    unsigned long long* eOut = (k & 1) ? eBuf0 : eBuf1;
    int* rIn  = (k & 1) ? rBuf1 : rBuf0;
    int* rOut = (k & 1) ? rBuf0 : rBuf1;
    k_esim_edge<<<gN, blk, 0, stream>>>(eIn, ctr+64+(k-2)*8, eOut, ctr+64+(k-1)*8,
                                        par, fsum, cnt, mk, (unsigned)(k+1));
    k_eupd<<<gN, blk, 0, stream>>>(rIn, ctr+(k-1)*8, rOut, ctr+k*8, mk,
                                   (unsigned)(k+1), par, fsum, psum, cnt);
  }

  float* out = (float*)d_out;
  k_final<<<gN, blk, 0, stream>>>(par, img, cnt, fsum, psum, lw, lb,
                                  out, out + (size_t)N_*C_);
}

// Round 10
// 174.202 us; speedup vs baseline: 13.0302x; 13.0302x over previous
//
#include <hip/hip_runtime.h>

#define B_ 8
#define C_ 3
#define H_ 256
#define W_ 256
#define HID_ 32
#define HW_ (H_*W_)            // 65536
#define N_ (B_*H_*W_)          // 524288
#define K01_ 0xBDCCCCCDu       // fkey(0.1f)
#define TILE_ 16

// XCD-chunked swizzle for 2048-block grids: consecutive hardware block ids
// round-robin across 8 XCDs; remap so XCD x owns image x -> region atomics
// and chase reads stay in one L2.
__device__ __forceinline__ int swz2048(int bid){ return ((bid & 7) << 8) | (bid >> 3); }

__device__ __forceinline__ unsigned fkey(float f){
  unsigned u = __float_as_uint(f);
  return (u & 0x80000000u) ? ~u : (u | 0x80000000u);
}

// mk entry: [63:56]=tag(it+1) | [55:24]=fkey(sim) | [23:0]=neighbor id (N<2^24).
// atomicMax: newer tag always wins; same tag -> (key,id) lexicographic max,
// which is exactly the reference's "max rb among sim==maxsim" tie-break.
__device__ __forceinline__ unsigned long long pack_mk(unsigned tag, unsigned key, int id){
  return ((unsigned long long)tag << 56) | ((unsigned long long)key << 24) | (unsigned)id;
}

__device__ __forceinline__ int parent_dec(unsigned long long m, unsigned tag, int x){
  if ((unsigned)(m >> 56) != tag) return x;
  return ((unsigned)(m >> 24) > K01_) ? (int)(m & 0xFFFFFFu) : x;
}

// 16x16-tile conv + init + it0 in-tile sims (img tile in LDS, sims via wave
// shuffles; lane layout r = wv*4 + (lane>>4), c = lane&15). Weights padded to
// [32][28] so the inner loop reads them as 7 float4 LDS broadcasts per oc
// (4x fewer LDS ops); fmaf chain keeps the exact accumulation order.
__global__ __launch_bounds__(256) void k_conv_init(const float* __restrict__ img,
    const float* __restrict__ cw, const float* __restrict__ cb,
    float* __restrict__ fsum, int* __restrict__ labels,
    float* __restrict__ cnt, float* __restrict__ psum,
    unsigned long long* __restrict__ mk, int* __restrict__ mflag){
  __shared__ __align__(16) float w_s[HID_][28];   // 27 weights + zero pad
  __shared__ float b_s[HID_];
  __shared__ float img_s[C_][TILE_+2][TILE_+3];   // 3 x 18 x 19
  __shared__ float rowbuf[3*TILE_][33];           // rows 4,8,12 cross-wave
  for (int t = threadIdx.x; t < HID_*28; t += blockDim.x){
    int oc = t / 28, e = t - oc*28;
    w_s[oc][e] = (e < 27) ? cw[oc*27 + e] : 0.f;
  }
  if (threadIdx.x < HID_) b_s[threadIdx.x] = cb[threadIdx.x];
  if (blockIdx.x == 0 && threadIdx.x < 16) mflag[threadIdx.x] = 0;

  int sb = swz2048(blockIdx.x);
  int b  = sb >> 8;
  int ti = sb & 255;
  int h0 = (ti >> 4) * TILE_;
  int w0 = (ti & 15) * TILE_;

  // stage img tile (18x18x3) with zero padding
  for (int t = threadIdx.x; t < C_*18*18; t += blockDim.x){
    int ci = t / 324; int rm = t - ci*324; int rr = rm / 18; int cc = rm - rr*18;
    int hh = h0 - 1 + rr, ww = w0 - 1 + cc;
    float v = 0.f;
    if (hh >= 0 && hh < H_ && ww >= 0 && ww < W_)
      v = img[(size_t)(b*C_+ci)*HW_ + hh*W_ + ww];
    img_s[ci][rr][cc] = v;
  }
  __syncthreads();

  int lane = threadIdx.x & 63, wv = threadIdx.x >> 6;
  int r = wv*4 + (lane >> 4);
  int c = lane & 15;
  int h = h0 + r, w = w0 + c;
  int i = (b << 16) | (h << 8) | w;

  float patch[28];
  #pragma unroll
  for (int ci=0; ci<C_; ++ci)
    #pragma unroll
    for (int kh=0; kh<3; ++kh)
      #pragma unroll
      for (int kw=0; kw<3; ++kw)
        patch[ci*9+kh*3+kw] = img_s[ci][r+kh][c+kw];
  patch[27] = 0.f;

  float acc[HID_];
  #pragma unroll 4
  for (int oc=0; oc<HID_; ++oc){
    float a = b_s[oc];
    const float4* w4 = (const float4*)(&w_s[oc][0]);
    #pragma unroll
    for (int k7=0; k7<7; ++k7){
      float4 wv4 = w4[k7];                 // LDS broadcast, 1 instr / 4 weights
      a = fmaf(patch[k7*4+0], wv4.x, a);
      a = fmaf(patch[k7*4+1], wv4.y, a);
      a = fmaf(patch[k7*4+2], wv4.z, a);
      a = fmaf(patch[k7*4+3], wv4.w, a);
    }
    acc[oc] = a;
  }

  {
    float4* o4 = (float4*)(fsum + (size_t)i*HID_);
    #pragma unroll
    for (int k=0; k<HID_/4; ++k)
      o4[k] = make_float4(acc[4*k], acc[4*k+1], acc[4*k+2], acc[4*k+3]);
  }
  labels[i] = i;
  cnt[i] = 1.0f;
  #pragma unroll
  for (int cc=0; cc<C_; ++cc) psum[(size_t)i*C_+cc] = img_s[cc][r+1][c+1];

  // stage rows 4,8,12 (each wave's lanes 0..15) for cross-wave down edges
  if (wv >= 1 && lane < 16){
    float* dst = rowbuf[(wv-1)*TILE_ + c];
    #pragma unroll
    for (int d=0; d<HID_; ++d) dst[d] = acc[d];
  }

  float d2R = 0.f;
  #pragma unroll
  for (int k=0; k<HID_/4; ++k){
    float t0 = acc[4*k]   - __shfl_down(acc[4*k],  1);
    float t1 = acc[4*k+1] - __shfl_down(acc[4*k+1],1);
    float t2 = acc[4*k+2] - __shfl_down(acc[4*k+2],1);
    float t3 = acc[4*k+3] - __shfl_down(acc[4*k+3],1);
    d2R += t0*t0 + t1*t1 + t2*t2 + t3*t3;
  }
  float d2D = 0.f;
  #pragma unroll
  for (int k=0; k<HID_/4; ++k){
    float t0 = acc[4*k]   - __shfl_down(acc[4*k],  16);
    float t1 = acc[4*k+1] - __shfl_down(acc[4*k+1],16);
    float t2 = acc[4*k+2] - __shfl_down(acc[4*k+2],16);
    float t3 = acc[4*k+3] - __shfl_down(acc[4*k+3],16);
    d2D += t0*t0 + t1*t1 + t2*t2 + t3*t3;
  }
  __syncthreads();
  if (lane >= 48 && wv < 3){          // row 4wv+3: neighbor row in wave wv+1
    const float* nb = rowbuf[wv*TILE_ + c];
    d2D = 0.f;
    #pragma unroll
    for (int k=0; k<HID_/4; ++k){
      float t0 = acc[4*k]   - nb[4*k];
      float t1 = acc[4*k+1] - nb[4*k+1];
      float t2 = acc[4*k+2] - nb[4*k+2];
      float t3 = acc[4*k+3] - nb[4*k+3];
      d2D += t0*t0 + t1*t1 + t2*t2 + t3*t3;
    }
  }

  if (c < TILE_-1){
    unsigned key = fkey(expf(-d2R));
    atomicMax(mk+i,   pack_mk(1u, key, i+1));
    atomicMax(mk+i+1, pack_mk(1u, key, i));
  }
  if (r < TILE_-1){
    unsigned key = fkey(expf(-d2D));
    atomicMax(mk+i,     pack_mk(1u, key, i+W_));
    atomicMax(mk+i+W_,  pack_mk(1u, key, i));
  }
}

// cross-tile it0 edges: 8 images x {15 boundary cols x 256, 15 boundary rows x 256}
__global__ void k_bedge(const float* __restrict__ fsum,
                        unsigned long long* __restrict__ mk){
  int t = blockIdx.x*blockDim.x + threadIdx.x;
  if (t >= B_*2*15*256) return;
  int y  = t & 255;
  int k  = (t >> 8) % 15;
  int ty = (t >> 8) / 15;
  int b  = ty >> 1, tp = ty & 1;
  int i, j;
  if (tp == 0){ i = (b<<16) | (y<<8) | (16*k+15); j = i+1;  }
  else        { i = (b<<16) | ((16*k+15)<<8) | y; j = i+W_; }
  const float4* fa = (const float4*)(fsum + (size_t)i*HID_);
  const float4* fb = (const float4*)(fsum + (size_t)j*HID_);
  float d2 = 0.f;
  #pragma unroll
  for (int q=0; q<HID_/4; ++q){
    float4 va = fa[q], vb = fb[q];
    float t0 = va.x-vb.x, t1 = va.y-vb.y, t2 = va.z-vb.z, t3 = va.w-vb.w;
    d2 += t0*t0 + t1*t1 + t2*t2 + t3*t3;
  }
  unsigned key = fkey(expf(-d2));
  atomicMax(mk+i, pack_mk(1u, key, j));
  atomicMax(mk+j, pack_mk(1u, key, i));
}

// mid-iteration fused sim+best, 1 px/thread, XCD-swizzled.
// Converged early-exit: if iteration tag-1 performed zero merges, sims are
// unchanged and no further merges can occur (absorbing) -> return.
__global__ void k_simbest(const int* __restrict__ labels,
                          const float* __restrict__ fsum, const float* __restrict__ cnt,
                          unsigned long long* __restrict__ mk, unsigned tag,
                          const int* __restrict__ mflag){
  if (mflag[tag-1] == 0) return;     // tag>=2 always (loop starts at it=1)
  int i = swz2048(blockIdx.x)*256 + threadIdx.x;
  int rem = i & (HW_-1); int h = rem >> 8; int w = rem & (W_-1);
  int ri = labels[i];
  int rR = (w < W_-1) ? labels[i+1]  : ri;
  int rD = (h < H_-1) ? labels[i+W_] : ri;
  bool eR = (rR != ri), eD = (rD != ri);
  if (!eR && !eD) return;
  float rci = 1.0f / cnt[ri];
  const float4* fi = (const float4*)(fsum + (size_t)ri*HID_);
  float4 mi[HID_/4];
  #pragma unroll
  for (int k=0; k<HID_/4; ++k){
    float4 v = fi[k];
    mi[k] = make_float4(v.x*rci, v.y*rci, v.z*rci, v.w*rci);
  }
  if (eR){
    float rcj = 1.0f / cnt[rR];
    const float4* fj = (const float4*)(fsum + (size_t)rR*HID_);
    float d2 = 0.f;
    #pragma unroll
    for (int k=0; k<HID_/4; ++k){
      float4 v = fj[k];
      float tx = mi[k].x - v.x*rcj; float ty = mi[k].y - v.y*rcj;
      float tz = mi[k].z - v.z*rcj; float tw = mi[k].w - v.w*rcj;
      d2 += tx*tx + ty*ty + tz*tz + tw*tw;
    }
    unsigned key = fkey(expf(-d2));
    atomicMax(mk+ri, pack_mk(tag, key, rR));
    atomicMax(mk+rR, pack_mk(tag, key, ri));
  }
  if (eD){
    float rcj = 1.0f / cnt[rD];
    const float4* fj = (const float4*)(fsum + (size_t)rD*HID_);
    float d2 = 0.f;
    #pragma unroll
    for (int k=0; k<HID_/4; ++k){
      float4 v = fj[k];
      float tx = mi[k].x - v.x*rcj; float ty = mi[k].y - v.y*rcj;
      float tz = mi[k].z - v.z*rcj; float tw = mi[k].w - v.w*rcj;
      d2 += tx*tx + ty*ty + tz*tz + tw*tw;
    }
    unsigned key = fkey(expf(-d2));
    atomicMax(mk+ri, pack_mk(tag, key, rD));
    atomicMax(mk+rD, pack_mk(tag, key, ri));
  }
}

// chase + fold + relabel, 1 px/thread, XCD-swizzled. Sets mflag[tag] when any
// fold occurs; exits early when previous iteration was merge-free.
__global__ void k_update(const unsigned long long* __restrict__ mk, unsigned tag,
                         int* __restrict__ labels,
                         float* __restrict__ fsum, float* __restrict__ psum,
                         float* __restrict__ cnt, int* __restrict__ mflag){
  if (tag >= 2 && mflag[tag-1] == 0) return;
  int i = swz2048(blockIdx.x)*256 + threadIdx.x;
  int l = labels[i];
  int x = l;
  for (int it = 0; it < (1<<20); ++it){
    int p = parent_dec(mk[x], tag, x);
    if (p == x) break;
    int pp = parent_dec(mk[p], tag, p);
    if (pp == x && x < p) break;     // broken 2-cycle: x is the root
    x = p;
  }
  if (l == i && x != i){             // dying root: fold into surviving root
    mflag[tag] = 1;
    atomicAdd(cnt+x, cnt[i]);
    const float* s = fsum + (size_t)i*HID_;
    float* ds = fsum + (size_t)x*HID_;
    #pragma unroll
    for (int d=0; d<HID_; ++d) atomicAdd(ds+d, s[d]);
    const float* ps = psum + (size_t)i*C_;
    float* dp = psum + (size_t)x*C_;
    #pragma unroll
    for (int cc=0; cc<C_; ++cc) atomicAdd(dp+cc, ps[cc]);
  }
  labels[i] = x;
}

// finalize: region feature recomputed at root (roots L2-hot within the XCD's
// image slab), mean injection, labels as float.
__global__ __launch_bounds__(256) void k_out(const int* __restrict__ labels,
      const float* __restrict__ img, const float* __restrict__ cnt,
      const float* __restrict__ fsum, const float* __restrict__ psum,
      const float* __restrict__ lw, const float* __restrict__ lb,
      float* __restrict__ out, float* __restrict__ outlab){
  __shared__ float lw_s[C_*HID_];
  __shared__ float lb_s[C_];
  for (int t = threadIdx.x; t < C_*HID_; t += blockDim.x) lw_s[t] = lw[t];
  if (threadIdx.x < C_) lb_s[threadIdx.x] = lb[threadIdx.x];
  __syncthreads();
  int i = swz2048(blockIdx.x)*256 + threadIdx.x;
  int l = labels[i];
  float rc = 1.0f / cnt[l];
  const float* s = fsum + (size_t)l*HID_;
  float rf[C_];
  #pragma unroll
  for (int cc=0; cc<C_; ++cc){
    float a = 0.f;
    const float* wv = lw_s + cc*HID_;
    #pragma unroll
    for (int d=0; d<HID_; ++d) a += (s[d]*rc)*wv[d];
    rf[cc] = (a + lb_s[cc]) - psum[(size_t)l*C_+cc]*rc;
  }
  int b = i >> 16; int rem = i & (HW_-1);
  const float* ip = img + (size_t)b*C_*HW_ + rem;
  #pragma unroll
  for (int cc=0; cc<C_; ++cc)
    out[(size_t)i*C_+cc] = ip[(size_t)cc*HW_] + rf[cc];
  outlab[i] = (float)l;
}

extern "C" void kernel_launch(void* const* d_in, const int* in_sizes, int n_in,
                              void* d_out, int out_size, void* d_ws, size_t ws_size,
                              hipStream_t stream) {
  const float* img = (const float*)d_in[0];
  const float* cw  = (const float*)d_in[1];
  const float* cb  = (const float*)d_in[2];
  const float* lw  = (const float*)d_in[3];
  const float* lb  = (const float*)d_in[4];

  char* ws = (char*)d_ws;
  size_t off = 0;
  auto alloc = [&](size_t bytes) -> void* {
    void* p = ws + off; off += (bytes + 255) & ~(size_t)255; return p;
  };
  float*              fsum   = (float*)              alloc((size_t)N_*HID_*4);
  float*              psum   = (float*)              alloc((size_t)N_*C_*4);
  float*              cnt    = (float*)              alloc((size_t)N_*4);
  unsigned long long* mk     = (unsigned long long*) alloc((size_t)N_*8);
  int*                labels = (int*)                alloc((size_t)N_*4);
  int*                mflag  = (int*)                alloc(64);

  dim3 blk(256);
  const int gN = 2048;

  hipMemsetAsync(mk, 0, (size_t)N_*8, stream);   // clear 0xAA poison (tag field)
  k_conv_init<<<gN, blk, 0, stream>>>(img, cw, cb, fsum, labels, cnt, psum, mk, mflag);
  k_bedge<<<240, blk, 0, stream>>>(fsum, mk);
  k_update<<<gN, blk, 0, stream>>>(mk, 1u, labels, fsum, psum, cnt, mflag);

  for (int it = 1; it < 8; ++it) {
    k_simbest<<<gN, blk, 0, stream>>>(labels, fsum, cnt, mk, (unsigned)(it+1), mflag);
    k_update<<<gN, blk, 0, stream>>>(mk, (unsigned)(it+1), labels, fsum, psum, cnt, mflag);
  }

  float* out = (float*)d_out;
  k_out<<<gN, blk, 0, stream>>>(labels, img, cnt, fsum, psum, lw, lb,
                                out, out + (size_t)N_*C_);
}

// Round 11
// 170.247 us; speedup vs baseline: 13.3329x; 1.0232x over previous
//
#include <hip/hip_runtime.h>

#define B_ 8
#define C_ 3
#define H_ 256
#define W_ 256
#define HID_ 32
#define HW_ (H_*W_)            // 65536
#define N_ (B_*H_*W_)          // 524288
#define K01_ 0xBDCCCCCDu       // fkey(0.1f)
#define TILE_ 16

// XCD-chunked swizzle for 2048-block grids: consecutive hardware block ids
// round-robin across 8 XCDs; remap so XCD x owns image x -> region atomics
// and chase reads stay in one L2.
__device__ __forceinline__ int swz2048(int bid){ return ((bid & 7) << 8) | (bid >> 3); }

__device__ __forceinline__ unsigned fkey(float f){
  unsigned u = __float_as_uint(f);
  return (u & 0x80000000u) ? ~u : (u | 0x80000000u);
}

// mk entry: [63:56]=tag(it+1) | [55:24]=fkey(sim) | [23:0]=neighbor id (N<2^24).
// atomicMax: newer tag always wins; same tag -> (key,id) lexicographic max,
// which is exactly the reference's "max rb among sim==maxsim" tie-break.
__device__ __forceinline__ unsigned long long pack_mk(unsigned tag, unsigned key, int id){
  return ((unsigned long long)tag << 56) | ((unsigned long long)key << 24) | (unsigned)id;
}

__device__ __forceinline__ int parent_dec(unsigned long long m, unsigned tag, int x){
  if ((unsigned)(m >> 56) != tag) return x;
  return ((unsigned)(m >> 24) > K01_) ? (int)(m & 0xFFFFFFu) : x;
}

// 16x16-tile conv + init + it0 in-tile sims (img tile in LDS, sims via wave
// shuffles; lane layout r = wv*4 + (lane>>4), c = lane&15). Weights padded to
// [32][28], read as 7 float4 LDS broadcasts per oc; fmaf chain keeps exact
// accumulation order. Also clears mk[i] (replaces the 4MB memset: all in-tile
// mk atomics stay in this block, cross-tile edges run later in k_bedge, so
// clear-before-atomics is guaranteed by the in-block __syncthreads).
__global__ __launch_bounds__(256) void k_conv_init(const float* __restrict__ img,
    const float* __restrict__ cw, const float* __restrict__ cb,
    float* __restrict__ fsum, int* __restrict__ labels,
    float* __restrict__ cnt, float* __restrict__ psum,
    unsigned long long* __restrict__ mk, int* __restrict__ mflag){
  __shared__ __align__(16) float w_s[HID_][28];   // 27 weights + zero pad
  __shared__ float b_s[HID_];
  __shared__ float img_s[C_][TILE_+2][TILE_+3];   // 3 x 18 x 19
  __shared__ float rowbuf[3*TILE_][33];           // rows 4,8,12 cross-wave
  for (int t = threadIdx.x; t < HID_*28; t += blockDim.x){
    int oc = t / 28, e = t - oc*28;
    w_s[oc][e] = (e < 27) ? cw[oc*27 + e] : 0.f;
  }
  if (threadIdx.x < HID_) b_s[threadIdx.x] = cb[threadIdx.x];
  if (blockIdx.x == 0 && threadIdx.x < 16) mflag[threadIdx.x] = 0;

  int sb = swz2048(blockIdx.x);
  int b  = sb >> 8;
  int ti = sb & 255;
  int h0 = (ti >> 4) * TILE_;
  int w0 = (ti & 15) * TILE_;

  int lane = threadIdx.x & 63, wv = threadIdx.x >> 6;
  int r = wv*4 + (lane >> 4);
  int c = lane & 15;
  int h = h0 + r, w = w0 + c;
  int i = (b << 16) | (h << 8) | w;

  mk[i] = 0ULL;                      // clear before this block's atomics (sync below)

  // stage img tile (18x18x3) with zero padding
  for (int t = threadIdx.x; t < C_*18*18; t += blockDim.x){
    int ci = t / 324; int rm = t - ci*324; int rr = rm / 18; int cc = rm - rr*18;
    int hh = h0 - 1 + rr, ww = w0 - 1 + cc;
    float v = 0.f;
    if (hh >= 0 && hh < H_ && ww >= 0 && ww < W_)
      v = img[(size_t)(b*C_+ci)*HW_ + hh*W_ + ww];
    img_s[ci][rr][cc] = v;
  }
  __syncthreads();

  float patch[28];
  #pragma unroll
  for (int ci=0; ci<C_; ++ci)
    #pragma unroll
    for (int kh=0; kh<3; ++kh)
      #pragma unroll
      for (int kw=0; kw<3; ++kw)
        patch[ci*9+kh*3+kw] = img_s[ci][r+kh][c+kw];
  patch[27] = 0.f;

  float acc[HID_];
  #pragma unroll 4
  for (int oc=0; oc<HID_; ++oc){
    float a = b_s[oc];
    const float4* w4 = (const float4*)(&w_s[oc][0]);
    #pragma unroll
    for (int k7=0; k7<7; ++k7){
      float4 wv4 = w4[k7];                 // LDS broadcast, 1 instr / 4 weights
      a = fmaf(patch[k7*4+0], wv4.x, a);
      a = fmaf(patch[k7*4+1], wv4.y, a);
      a = fmaf(patch[k7*4+2], wv4.z, a);
      a = fmaf(patch[k7*4+3], wv4.w, a);
    }
    acc[oc] = a;
  }

  {
    float4* o4 = (float4*)(fsum + (size_t)i*HID_);
    #pragma unroll
    for (int k=0; k<HID_/4; ++k)
      o4[k] = make_float4(acc[4*k], acc[4*k+1], acc[4*k+2], acc[4*k+3]);
  }
  labels[i] = i;
  cnt[i] = 1.0f;
  #pragma unroll
  for (int cc=0; cc<C_; ++cc) psum[(size_t)i*C_+cc] = img_s[cc][r+1][c+1];

  // stage rows 4,8,12 (each wave's lanes 0..15) for cross-wave down edges
  if (wv >= 1 && lane < 16){
    float* dst = rowbuf[(wv-1)*TILE_ + c];
    #pragma unroll
    for (int d=0; d<HID_; ++d) dst[d] = acc[d];
  }

  float d2R = 0.f;
  #pragma unroll
  for (int k=0; k<HID_/4; ++k){
    float t0 = acc[4*k]   - __shfl_down(acc[4*k],  1);
    float t1 = acc[4*k+1] - __shfl_down(acc[4*k+1],1);
    float t2 = acc[4*k+2] - __shfl_down(acc[4*k+2],1);
    float t3 = acc[4*k+3] - __shfl_down(acc[4*k+3],1);
    d2R += t0*t0 + t1*t1 + t2*t2 + t3*t3;
  }
  float d2D = 0.f;
  #pragma unroll
  for (int k=0; k<HID_/4; ++k){
    float t0 = acc[4*k]   - __shfl_down(acc[4*k],  16);
    float t1 = acc[4*k+1] - __shfl_down(acc[4*k+1],16);
    float t2 = acc[4*k+2] - __shfl_down(acc[4*k+2],16);
    float t3 = acc[4*k+3] - __shfl_down(acc[4*k+3],16);
    d2D += t0*t0 + t1*t1 + t2*t2 + t3*t3;
  }
  __syncthreads();
  if (lane >= 48 && wv < 3){          // row 4wv+3: neighbor row in wave wv+1
    const float* nb = rowbuf[wv*TILE_ + c];
    d2D = 0.f;
    #pragma unroll
    for (int k=0; k<HID_/4; ++k){
      float t0 = acc[4*k]   - nb[4*k];
      float t1 = acc[4*k+1] - nb[4*k+1];
      float t2 = acc[4*k+2] - nb[4*k+2];
      float t3 = acc[4*k+3] - nb[4*k+3];
      d2D += t0*t0 + t1*t1 + t2*t2 + t3*t3;
    }
  }

  if (c < TILE_-1){
    unsigned key = fkey(expf(-d2R));
    atomicMax(mk+i,   pack_mk(1u, key, i+1));
    atomicMax(mk+i+1, pack_mk(1u, key, i));
  }
  if (r < TILE_-1){
    unsigned key = fkey(expf(-d2D));
    atomicMax(mk+i,     pack_mk(1u, key, i+W_));
    atomicMax(mk+i+W_,  pack_mk(1u, key, i));
  }
}

// cross-tile it0 edges: 8 images x {15 boundary cols x 256, 15 boundary rows x 256}
__global__ void k_bedge(const float* __restrict__ fsum,
                        unsigned long long* __restrict__ mk){
  int t = blockIdx.x*blockDim.x + threadIdx.x;
  if (t >= B_*2*15*256) return;
  int y  = t & 255;
  int k  = (t >> 8) % 15;
  int ty = (t >> 8) / 15;
  int b  = ty >> 1, tp = ty & 1;
  int i, j;
  if (tp == 0){ i = (b<<16) | (y<<8) | (16*k+15); j = i+1;  }
  else        { i = (b<<16) | ((16*k+15)<<8) | y; j = i+W_; }
  const float4* fa = (const float4*)(fsum + (size_t)i*HID_);
  const float4* fb = (const float4*)(fsum + (size_t)j*HID_);
  float d2 = 0.f;
  #pragma unroll
  for (int q=0; q<HID_/4; ++q){
    float4 va = fa[q], vb = fb[q];
    float t0 = va.x-vb.x, t1 = va.y-vb.y, t2 = va.z-vb.z, t3 = va.w-vb.w;
    d2 += t0*t0 + t1*t1 + t2*t2 + t3*t3;
  }
  unsigned key = fkey(expf(-d2));
  atomicMax(mk+i, pack_mk(1u, key, j));
  atomicMax(mk+j, pack_mk(1u, key, i));
}

// mid-iteration fused sim+best, 1 px/thread, XCD-swizzled.
// Converged early-exit: if iteration tag-1 performed zero merges, sims are
// unchanged and no further merges can occur (absorbing) -> return.
__global__ void k_simbest(const int* __restrict__ labels,
                          const float* __restrict__ fsum, const float* __restrict__ cnt,
                          unsigned long long* __restrict__ mk, unsigned tag,
                          const int* __restrict__ mflag){
  if (mflag[tag-1] == 0) return;     // tag>=2 always (loop starts at it=1)
  int i = swz2048(blockIdx.x)*256 + threadIdx.x;
  int rem = i & (HW_-1); int h = rem >> 8; int w = rem & (W_-1);
  int ri = labels[i];
  int rR = (w < W_-1) ? labels[i+1]  : ri;
  int rD = (h < H_-1) ? labels[i+W_] : ri;
  bool eR = (rR != ri), eD = (rD != ri);
  if (!eR && !eD) return;
  float rci = 1.0f / cnt[ri];
  const float4* fi = (const float4*)(fsum + (size_t)ri*HID_);
  float4 mi[HID_/4];
  #pragma unroll
  for (int k=0; k<HID_/4; ++k){
    float4 v = fi[k];
    mi[k] = make_float4(v.x*rci, v.y*rci, v.z*rci, v.w*rci);
  }
  if (eR){
    float rcj = 1.0f / cnt[rR];
    const float4* fj = (const float4*)(fsum + (size_t)rR*HID_);
    float d2 = 0.f;
    #pragma unroll
    for (int k=0; k<HID_/4; ++k){
      float4 v = fj[k];
      float tx = mi[k].x - v.x*rcj; float ty = mi[k].y - v.y*rcj;
      float tz = mi[k].z - v.z*rcj; float tw = mi[k].w - v.w*rcj;
      d2 += tx*tx + ty*ty + tz*tz + tw*tw;
    }
    unsigned key = fkey(expf(-d2));
    atomicMax(mk+ri, pack_mk(tag, key, rR));
    atomicMax(mk+rR, pack_mk(tag, key, ri));
  }
  if (eD){
    float rcj = 1.0f / cnt[rD];
    const float4* fj = (const float4*)(fsum + (size_t)rD*HID_);
    float d2 = 0.f;
    #pragma unroll
    for (int k=0; k<HID_/4; ++k){
      float4 v = fj[k];
      float tx = mi[k].x - v.x*rcj; float ty = mi[k].y - v.y*rcj;
      float tz = mi[k].z - v.z*rcj; float tw = mi[k].w - v.w*rcj;
      d2 += tx*tx + ty*ty + tz*tz + tw*tw;
    }
    unsigned key = fkey(expf(-d2));
    atomicMax(mk+ri, pack_mk(tag, key, rD));
    atomicMax(mk+rD, pack_mk(tag, key, ri));
  }
}

// chase + fold + relabel, 1 px/thread, XCD-swizzled. Sets mflag[tag] when any
// fold occurs; exits early when previous iteration was merge-free.
__global__ void k_update(const unsigned long long* __restrict__ mk, unsigned tag,
                         int* __restrict__ labels,
                         float* __restrict__ fsum, float* __restrict__ psum,
                         float* __restrict__ cnt, int* __restrict__ mflag){
  if (tag >= 2 && mflag[tag-1] == 0) return;
  int i = swz2048(blockIdx.x)*256 + threadIdx.x;
  int l = labels[i];
  int x = l;
  for (int it = 0; it < (1<<20); ++it){
    int p = parent_dec(mk[x], tag, x);
    if (p == x) break;
    int pp = parent_dec(mk[p], tag, p);
    if (pp == x && x < p) break;     // broken 2-cycle: x is the root
    x = p;
  }
  if (l == i && x != i){             // dying root: fold into surviving root
    mflag[tag] = 1;
    atomicAdd(cnt+x, cnt[i]);
    const float* s = fsum + (size_t)i*HID_;
    float* ds = fsum + (size_t)x*HID_;
    #pragma unroll
    for (int d=0; d<HID_; ++d) atomicAdd(ds+d, s[d]);
    const float* ps = psum + (size_t)i*C_;
    float* dp = psum + (size_t)x*C_;
    #pragma unroll
    for (int cc=0; cc<C_; ++cc) atomicAdd(dp+cc, ps[cc]);
  }
  labels[i] = x;
}

// finalize: region feature recomputed at root (roots L2-hot within the XCD's
// image slab), mean injection, labels as float.
__global__ __launch_bounds__(256) void k_out(const int* __restrict__ labels,
      const float* __restrict__ img, const float* __restrict__ cnt,
      const float* __restrict__ fsum, const float* __restrict__ psum,
      const float* __restrict__ lw, const float* __restrict__ lb,
      float* __restrict__ out, float* __restrict__ outlab){
  __shared__ float lw_s[C_*HID_];
  __shared__ float lb_s[C_];
  for (int t = threadIdx.x; t < C_*HID_; t += blockDim.x) lw_s[t] = lw[t];
  if (threadIdx.x < C_) lb_s[threadIdx.x] = lb[threadIdx.x];
  __syncthreads();
  int i = swz2048(blockIdx.x)*256 + threadIdx.x;
  int l = labels[i];
  float rc = 1.0f / cnt[l];
  const float* s = fsum + (size_t)l*HID_;
  float rf[C_];
  #pragma unroll
  for (int cc=0; cc<C_; ++cc){
    float a = 0.f;
    const float* wv = lw_s + cc*HID_;
    #pragma unroll
    for (int d=0; d<HID_; ++d) a += (s[d]*rc)*wv[d];
    rf[cc] = (a + lb_s[cc]) - psum[(size_t)l*C_+cc]*rc;
  }
  int b = i >> 16; int rem = i & (HW_-1);
  const float* ip = img + (size_t)b*C_*HW_ + rem;
  #pragma unroll
  for (int cc=0; cc<C_; ++cc)
    out[(size_t)i*C_+cc] = ip[(size_t)cc*HW_] + rf[cc];
  outlab[i] = (float)l;
}

extern "C" void kernel_launch(void* const* d_in, const int* in_sizes, int n_in,
                              void* d_out, int out_size, void* d_ws, size_t ws_size,
                              hipStream_t stream) {
  const float* img = (const float*)d_in[0];
  const float* cw  = (const float*)d_in[1];
  const float* cb  = (const float*)d_in[2];
  const float* lw  = (const float*)d_in[3];
  const float* lb  = (const float*)d_in[4];

  char* ws = (char*)d_ws;
  size_t off = 0;
  auto alloc = [&](size_t bytes) -> void* {
    void* p = ws + off; off += (bytes + 255) & ~(size_t)255; return p;
  };
  float*              fsum   = (float*)              alloc((size_t)N_*HID_*4);
  float*              psum   = (float*)              alloc((size_t)N_*C_*4);
  float*              cnt    = (float*)              alloc((size_t)N_*4);
  unsigned long long* mk     = (unsigned long long*) alloc((size_t)N_*8);
  int*                labels = (int*)                alloc((size_t)N_*4);
  int*                mflag  = (int*)                alloc(64);

  dim3 blk(256);
  const int gN = 2048;

  k_conv_init<<<gN, blk, 0, stream>>>(img, cw, cb, fsum, labels, cnt, psum, mk, mflag);
  k_bedge<<<240, blk, 0, stream>>>(fsum, mk);
  k_update<<<gN, blk, 0, stream>>>(mk, 1u, labels, fsum, psum, cnt, mflag);

  for (int it = 1; it < 8; ++it) {
    k_simbest<<<gN, blk, 0, stream>>>(labels, fsum, cnt, mk, (unsigned)(it+1), mflag);
    k_update<<<gN, blk, 0, stream>>>(mk, (unsigned)(it+1), labels, fsum, psum, cnt, mflag);
  }

  float* out = (float*)d_out;
  k_out<<<gN, blk, 0, stream>>>(labels, img, cnt, fsum, psum, lw, lb,
                                out, out + (size_t)N_*C_);
}